// Round 10
// baseline (1234.555 us; speedup 1.0000x reference)
//
#include <hip/hip_runtime.h>

#define Bn 32
#define Tn 512
#define Dn 512
#define Vn 512

typedef float f4 __attribute__((ext_vector_type(4)));
typedef int i8v __attribute__((ext_vector_type(8)));

__device__ __forceinline__ float max8lds(const float* p) {
  float4 a = *(const float4*)p;
  float4 b = *(const float4*)(p + 4);
  return fmaxf(fmaxf(fmaxf(a.x, a.y), fmaxf(a.z, a.w)),
               fmaxf(fmaxf(b.x, b.y), fmaxf(b.z, b.w)));
}

// 64-lane max via DPP (row_shr 1/2/4/8 + bcast15/31), result broadcast via readlane
__device__ __forceinline__ float dpp64max(float x) {
  int t;
  t = __builtin_amdgcn_update_dpp(__float_as_int(x), __float_as_int(x), 0x111, 0xF, 0xF, false);
  x = fmaxf(x, __int_as_float(t));
  t = __builtin_amdgcn_update_dpp(__float_as_int(x), __float_as_int(x), 0x112, 0xF, 0xF, false);
  x = fmaxf(x, __int_as_float(t));
  t = __builtin_amdgcn_update_dpp(__float_as_int(x), __float_as_int(x), 0x114, 0xF, 0xF, false);
  x = fmaxf(x, __int_as_float(t));
  t = __builtin_amdgcn_update_dpp(__float_as_int(x), __float_as_int(x), 0x118, 0xF, 0xF, false);
  x = fmaxf(x, __int_as_float(t));
  t = __builtin_amdgcn_update_dpp(__float_as_int(x), __float_as_int(x), 0x142, 0xF, 0xF, false);
  x = fmaxf(x, __int_as_float(t));
  t = __builtin_amdgcn_update_dpp(__float_as_int(x), __float_as_int(x), 0x143, 0xF, 0xF, false);
  x = fmaxf(x, __int_as_float(t));
  return __int_as_float(__builtin_amdgcn_readlane(__float_as_int(x), 63));
}

// raw barrier: LDS-visibility only (no vmcnt drain -> global ops float across steps)
__device__ __forceinline__ void bar_lgkm() {
  asm volatile("s_waitcnt lgkmcnt(0)" ::: "memory");
  __builtin_amdgcn_s_barrier();
}

// ---- f32 -> OCP e4m3fn, round-to-nearest-even (x >= 0 assumed) ----
__device__ __forceinline__ unsigned int f32_to_e4m3(float x) {
  x = fminf(x, 448.0f);
  unsigned int bits = __float_as_uint(x);
  int e = (int)((bits >> 23) & 0xFF) - 127;
  if (e < -6) {
    return (unsigned int)__float2int_rn(x * 512.0f);
  }
  unsigned int man = bits & 0x7FFFFF;
  int te = e + 7;
  unsigned int r = man >> 20;
  unsigned int rem = man & 0xFFFFF;
  if (rem > 0x80000u || (rem == 0x80000u && (r & 1u))) r++;
  if (r == 8u) { r = 0u; te++; }
  if (te > 15) { te = 15; r = 6u; }
  unsigned int byte = ((unsigned int)te << 3) | r;
  if (byte > 0x7Eu) byte = 0x7Eu;
  return byte;
}

// ---- pruning radius: max over columns v of (max_u T[u][v] - min_u T[u][v]) ----
__global__ __launch_bounds__(512) void crf_minmax(const float* __restrict__ trans,
                                                  unsigned int* __restrict__ Rout) {
  __shared__ float smn[8][64], smx[8][64];
  const int c = threadIdx.x & 63;
  const int seg = threadIdx.x >> 6;
  const int col = (int)blockIdx.x * 64 + c;
  float mn = 3e38f, mx = -3e38f;
#pragma unroll 4
  for (int u = seg * 64; u < seg * 64 + 64; ++u) {
    float t = trans[(size_t)u * Vn + col];
    mn = fminf(mn, t); mx = fmaxf(mx, t);
  }
  smn[seg][c] = mn; smx[seg][c] = mx;
  __syncthreads();
  if (seg == 0) {
#pragma unroll
    for (int i = 1; i < 8; ++i) { mn = fminf(mn, smn[i][c]); mx = fmaxf(mx, smx[i][c]); }
    float r = dpp64max(mx - mn);  // r >= 0
    if (c == 0) atomicMax((int*)Rout, __float_as_int(r));
  }
}

// ---- E8: exp(trans) as fp8 e4m3 MFMA A-fragments for 16x16x128 ----
// frag (vt, kc): byte index = lane*32 + j
//   u = kc*128 + 32*(lane>>4) + j,  v = vt*16 + (lane&15)
__global__ __launch_bounds__(256) void crf_build_E8(const float* __restrict__ trans,
                                                    unsigned char* __restrict__ E8) {
  const int fid = (int)blockIdx.x;       // 0..127 = vt*4 + kc
  const int vt = fid >> 2, kc = fid & 3;
  const int t = threadIdx.x;             // 8 bytes per thread
  const int lane = t >> 2;
  const int j0 = (t & 3) * 8;
  const int v = vt * 16 + (lane & 15);
  const int ubase = kc * 128 + (lane >> 4) * 32 + j0;
  unsigned long long pack = 0;
#pragma unroll
  for (int s = 0; s < 8; ++s) {
    float e = __expf(trans[(size_t)(ubase + s) * Vn + v]);
    pack |= (unsigned long long)f32_to_e4m3(e) << (8 * s);
  }
  *(unsigned long long*)(E8 + (size_t)fid * 2048 + lane * 32 + j0) = pack;
}

// ---- emissions = X(16384x512) * W^T(512x512), f32, 64x64 tile BK=16 ----
__global__ __launch_bounds__(256) void crf_gemm(const float* __restrict__ X,
                                                const float* __restrict__ Wt,
                                                float* __restrict__ C) {
  __shared__ float As[16][68];
  __shared__ float Bs[16][68];
  const int tid = threadIdx.x;
  const int m0 = (int)(blockIdx.x >> 3) * 64;
  const int v0 = (int)(blockIdx.x & 7) * 64;
  const int lr = tid >> 2;
  const int lk = (tid & 3) * 4;
  const int ty = tid >> 4, tx = tid & 15;
  float acc[4][4] = {};
  const float* xrow = X + (size_t)(m0 + lr) * Dn + lk;
  const float* wrow = Wt + (size_t)(v0 + lr) * Dn + lk;
  for (int k0 = 0; k0 < Dn; k0 += 16) {
    float4 av = *(const float4*)(xrow + k0);
    float4 bv = *(const float4*)(wrow + k0);
    __syncthreads();
    As[lk + 0][lr] = av.x; As[lk + 1][lr] = av.y; As[lk + 2][lr] = av.z; As[lk + 3][lr] = av.w;
    Bs[lk + 0][lr] = bv.x; Bs[lk + 1][lr] = bv.y; Bs[lk + 2][lr] = bv.z; Bs[lk + 3][lr] = bv.w;
    __syncthreads();
#pragma unroll
    for (int kk = 0; kk < 16; ++kk) {
      float4 a = *(const float4*)&As[kk][ty * 4];
      float4 b4 = *(const float4*)&Bs[kk][tx * 4];
      float a_[4] = {a.x, a.y, a.z, a.w};
      float b_[4] = {b4.x, b4.y, b4.z, b4.w};
#pragma unroll
      for (int j = 0; j < 4; ++j)
#pragma unroll
        for (int i = 0; i < 4; ++i)
          acc[j][i] = fmaf(a_[j], b_[i], acc[j][i]);
    }
  }
#pragma unroll
  for (int j = 0; j < 4; ++j) {
    float4 o; o.x = acc[j][0]; o.y = acc[j][1]; o.z = acc[j][2]; o.w = acc[j][3];
    *(float4*)(C + (size_t)(m0 + ty * 4 + j) * Vn + v0 + tx * 4) = o;
  }
}

// ---- shared-memory union: forward vs viterbi roles (2 batches per block) ----
union SM {
  struct {
    __align__(16) unsigned char ph[2][Vn];   // fp8 p per batch
    __align__(16) float wredA[8];
    __align__(16) float wredB[8];
    __align__(16) float wred2A[8];
    __align__(16) float wred2B[8];
    unsigned char padshA[Tn], padshB[Tn];
  } f;
  struct {
    __align__(16) float va2[2][2][Vn];       // parity, batch
    __align__(16) unsigned short bpbuf[32][Vn];
    unsigned short tokens[Tn];
    __align__(16) float wvals[8];
    int widxs[8];
    unsigned char padshA[Tn], padshB[Tn];
    int lastS;
  } v;
};

// ---- fused scan: blocks 0..15 forward (2 batches each); 16..31 viterbi (2 each) ----
__global__ __launch_bounds__(512, 2) void crf_scan(
    const float* __restrict__ emis, const float* __restrict__ trans,
    const unsigned char* __restrict__ E8, const float* __restrict__ Rp,
    const int* __restrict__ tgt, const unsigned char* __restrict__ pad,
    unsigned short* __restrict__ bps, float* __restrict__ out_ll,
    float* __restrict__ out_tok) {
  __shared__ SM sm;

  const int tid = threadIdx.x;
  const int role = (int)blockIdx.x >> 4;
  const int w = tid >> 6;
  const int lane = tid & 63;

  if (role == 0) {
    // ========== FORWARD: 2 batches interleaved, MX-FP8 MFMA K=128 ==========
    const int bA = (int)blockIdx.x * 2, bB = bA + 1;
    const float* ebA = emis + (size_t)bA * Tn * Vn;
    const float* ebB = emis + (size_t)bB * Tn * Vn;
    const int g = lane >> 4, c = lane & 15;
    const int t2sel = c >> 2, r2sel = c & 3;
    const int sidx = ((16 * ((lane >> 2) & 3)) + 4 * (lane >> 4) + (lane & 3)) << 2;
    i8v EA[4][4];
    {
      const i8v* E8v = (const i8v*)E8;
#pragma unroll
      for (int vt2 = 0; vt2 < 4; ++vt2)
#pragma unroll
        for (int kc = 0; kc < 4; ++kc)
          EA[vt2][kc] = E8v[((4 * w + vt2) * 4 + kc) * 64 + lane];
    }
    sm.f.padshA[tid] = pad[bA * Tn + tid];
    sm.f.padshB[tid] = pad[bB * Tn + tid];
    float alphaA = ebA[tid], alphaB = ebB[tid];
    float ecurA = ebA[Vn + tid], ecurB = ebB[Vn + tid];
    {
      float rA = dpp64max(alphaA);
      float rB = dpp64max(alphaB);
      if (lane == 0) { sm.f.wredA[w] = rA; sm.f.wredB[w] = rB; }
    }
    bar_lgkm();
    float mA = max8lds(sm.f.wredA);
    float mB = max8lds(sm.f.wredB);

    for (int t = 1; t < Tn; ++t) {
      float pA = __expf(alphaA - mA);
      float pB = __expf(alphaB - mB);
      sm.f.ph[0][tid] = (unsigned char)f32_to_e4m3(pA);
      sm.f.ph[1][tid] = (unsigned char)f32_to_e4m3(pB);
      bar_lgkm();  // bar1: ph visible
      float enA = (t + 1 < Tn) ? ebA[(size_t)(t + 1) * Vn + tid] : 0.f;
      float enB = (t + 1 < Tn) ? ebB[(size_t)(t + 1) * Vn + tid] : 0.f;
      const uint4* pqA = (const uint4*)sm.f.ph[0];
      const uint4* pqB = (const uint4*)sm.f.ph[1];
      f4 aA0 = (f4)(0.f), aA1 = (f4)(0.f), aA2 = (f4)(0.f), aA3 = (f4)(0.f);
      f4 aB0 = (f4)(0.f), aB1 = (f4)(0.f), aB2 = (f4)(0.f), aB3 = (f4)(0.f);
#pragma unroll
      for (int kc = 0; kc < 4; ++kc) {
        union { uint4 u[2]; i8v v; } xa, xb;
        xa.u[0] = pqA[kc * 8 + g * 2]; xa.u[1] = pqA[kc * 8 + g * 2 + 1];
        xb.u[0] = pqB[kc * 8 + g * 2]; xb.u[1] = pqB[kc * 8 + g * 2 + 1];
        aA0 = __builtin_amdgcn_mfma_scale_f32_16x16x128_f8f6f4(
            EA[0][kc], xa.v, aA0, 0, 0, 0, 0x7F7F7F7F, 0, 0x7F7F7F7F);
        aB0 = __builtin_amdgcn_mfma_scale_f32_16x16x128_f8f6f4(
            EA[0][kc], xb.v, aB0, 0, 0, 0, 0x7F7F7F7F, 0, 0x7F7F7F7F);
        aA1 = __builtin_amdgcn_mfma_scale_f32_16x16x128_f8f6f4(
            EA[1][kc], xa.v, aA1, 0, 0, 0, 0x7F7F7F7F, 0, 0x7F7F7F7F);
        aB1 = __builtin_amdgcn_mfma_scale_f32_16x16x128_f8f6f4(
            EA[1][kc], xb.v, aB1, 0, 0, 0, 0x7F7F7F7F, 0, 0x7F7F7F7F);
        aA2 = __builtin_amdgcn_mfma_scale_f32_16x16x128_f8f6f4(
            EA[2][kc], xa.v, aA2, 0, 0, 0, 0x7F7F7F7F, 0, 0x7F7F7F7F);
        aB2 = __builtin_amdgcn_mfma_scale_f32_16x16x128_f8f6f4(
            EA[2][kc], xb.v, aB2, 0, 0, 0, 0x7F7F7F7F, 0, 0x7F7F7F7F);
        aA3 = __builtin_amdgcn_mfma_scale_f32_16x16x128_f8f6f4(
            EA[3][kc], xa.v, aA3, 0, 0, 0, 0x7F7F7F7F, 0, 0x7F7F7F7F);
        aB3 = __builtin_amdgcn_mfma_scale_f32_16x16x128_f8f6f4(
            EA[3][kc], xb.v, aB3, 0, 0, 0, 0x7F7F7F7F, 0, 0x7F7F7F7F);
      }
      // lane (g,c) holds D[4g+r][c] of tile t2sel; bpermute redistributes to v=lane
      f4 atA = (t2sel == 0) ? aA0 : (t2sel == 1) ? aA1 : (t2sel == 2) ? aA2 : aA3;
      f4 atB = (t2sel == 0) ? aB0 : (t2sel == 1) ? aB1 : (t2sel == 2) ? aB2 : aB3;
      float loA = (r2sel & 1) ? atA[1] : atA[0];
      float hiA = (r2sel & 1) ? atA[3] : atA[2];
      float totA = (r2sel & 2) ? hiA : loA;
      float loB = (r2sel & 1) ? atB[1] : atB[0];
      float hiB = (r2sel & 1) ? atB[3] : atB[2];
      float totB = (r2sel & 2) ? hiB : loB;
      float tvA = __int_as_float(__builtin_amdgcn_ds_bpermute(sidx, __float_as_int(totA)));
      float tvB = __int_as_float(__builtin_amdgcn_ds_bpermute(sidx, __float_as_int(totB)));
      float nvA = mA + __logf(tvA) + ecurA;
      float nvB = mB + __logf(tvB) + ecurB;
      if (sm.f.padshA[t]) nvA = alphaA;
      if (sm.f.padshB[t]) nvB = alphaB;
      alphaA = nvA; ecurA = enA;
      alphaB = nvB; ecurB = enB;
      float rA = dpp64max(nvA);
      float rB = dpp64max(nvB);
      if (lane == 0) { sm.f.wredA[w] = rA; sm.f.wredB[w] = rB; }
      bar_lgkm();  // bar2: wred visible; ph safe to overwrite next iter
      mA = max8lds(sm.f.wredA);
      mB = max8lds(sm.f.wredB);
    }

    // epilogue: logZ + gold score for both batches
    __syncthreads();
    float exA = __expf(alphaA - mA);
    float exB = __expf(alphaB - mB);
#pragma unroll
    for (int off = 1; off < 64; off <<= 1) {
      exA += __shfl_xor(exA, off);
      exB += __shfl_xor(exB, off);
    }
    if (lane == 0) { sm.f.wredA[w] = exA; sm.f.wredB[w] = exB; }
    float scA, scB;
    {
      int tgA = tgt[bA * Tn + tid];
      float mtA = sm.f.padshA[tid] ? 0.f : 1.f;
      scA = ebA[(size_t)tid * Vn + tgA] * mtA;
      int tgB = tgt[bB * Tn + tid];
      float mtB = sm.f.padshB[tid] ? 0.f : 1.f;
      scB = ebB[(size_t)tid * Vn + tgB] * mtB;
      if (tid < Tn - 1) {
        int tgA1 = tgt[bA * Tn + tid + 1];
        float mtA1 = sm.f.padshA[tid + 1] ? 0.f : 1.f;
        scA += trans[(size_t)tgA * Vn + tgA1] * mtA * mtA1;
        int tgB1 = tgt[bB * Tn + tid + 1];
        float mtB1 = sm.f.padshB[tid + 1] ? 0.f : 1.f;
        scB += trans[(size_t)tgB * Vn + tgB1] * mtB * mtB1;
      }
    }
#pragma unroll
    for (int off = 1; off < 64; off <<= 1) {
      scA += __shfl_xor(scA, off);
      scB += __shfl_xor(scB, off);
    }
    if (lane == 0) { sm.f.wred2A[w] = scA; sm.f.wred2B[w] = scB; }
    __syncthreads();
    if (tid == 0) {
      float sA = 0.f, gA = 0.f, sB = 0.f, gB = 0.f;
      for (int i = 0; i < 8; ++i) {
        sA += sm.f.wredA[i]; gA += sm.f.wred2A[i];
        sB += sm.f.wredB[i]; gB += sm.f.wred2B[i];
      }
      out_ll[bA] = gA - (mA + __logf(sA));
      out_ll[bB] = gB - (mB + __logf(sB));
    }
  } else {
    // ========== VITERBI: 2 batches interleaved, global-threshold pruning ==========
    const int idx = (int)blockIdx.x - 16;
    const int bA = idx * 2, bB = bA + 1;
    const float* ebA = emis + (size_t)bA * Tn * Vn;
    const float* ebB = emis + (size_t)bB * Tn * Vn;
    float R = __int_as_float(((const int*)Rp)[0]) * 1.000001f + 1e-4f;
    sm.v.padshA[tid] = pad[bA * Tn + tid];
    sm.v.padshB[tid] = pad[bB * Tn + tid];
    float vaA = ebA[tid], vaB = ebB[tid];
    sm.v.va2[0][0][tid] = vaA;
    sm.v.va2[0][1][tid] = vaB;
    float ecurA = ebA[Vn + tid], ecurB = ebB[Vn + tid];
    bar_lgkm();

    for (int t = 1; t < Tn; ++t) {
      const int cur = t & 1, prev = cur ^ 1;
      const float* vpA = sm.v.va2[prev][0];
      const float* vpB = sm.v.va2[prev][1];
      const float4* vqA = (const float4*)vpA;
      const float4* vqB = (const float4*)vpB;
      float4 a0 = vqA[lane * 2], a1 = vqA[lane * 2 + 1];
      float4 b0 = vqB[lane * 2], b1 = vqB[lane * 2 + 1];
      float mxA = fmaxf(fmaxf(fmaxf(a0.x, a0.y), fmaxf(a0.z, a0.w)),
                        fmaxf(fmaxf(a1.x, a1.y), fmaxf(a1.z, a1.w)));
      float mxB = fmaxf(fmaxf(fmaxf(b0.x, b0.y), fmaxf(b0.z, b0.w)),
                        fmaxf(fmaxf(b1.x, b1.y), fmaxf(b1.z, b1.w)));
      float gA = dpp64max(mxA);
      float gB = dpp64max(mxB);
      float thrA = gA - R, thrB = gB - R;
      unsigned long long bmA[8], bmB[8];
      bmA[0] = __ballot(a0.x >= thrA); bmA[1] = __ballot(a0.y >= thrA);
      bmA[2] = __ballot(a0.z >= thrA); bmA[3] = __ballot(a0.w >= thrA);
      bmA[4] = __ballot(a1.x >= thrA); bmA[5] = __ballot(a1.y >= thrA);
      bmA[6] = __ballot(a1.z >= thrA); bmA[7] = __ballot(a1.w >= thrA);
      bmB[0] = __ballot(b0.x >= thrB); bmB[1] = __ballot(b0.y >= thrB);
      bmB[2] = __ballot(b0.z >= thrB); bmB[3] = __ballot(b0.w >= thrB);
      bmB[4] = __ballot(b1.x >= thrB); bmB[5] = __ballot(b1.y >= thrB);
      bmB[6] = __ballot(b1.z >= thrB); bmB[7] = __ballot(b1.w >= thrB);
      unsigned long long anyA = bmA[0] | bmA[1] | bmA[2] | bmA[3] |
                                bmA[4] | bmA[5] | bmA[6] | bmA[7];
      unsigned long long anyB = bmB[0] | bmB[1] | bmB[2] | bmB[3] |
                                bmB[4] | bmB[5] | bmB[6] | bmB[7];
      float enA = (t + 1 < Tn) ? ebA[(size_t)(t + 1) * Vn + tid] : 0.f;
      float enB = (t + 1 < Tn) ? ebB[(size_t)(t + 1) * Vn + tid] : 0.f;
      float bestA = -3e38f; int argA = 0;
      while (anyA) {
        int l = __ffsll(anyA) - 1; anyA &= anyA - 1;
#pragma unroll
        for (int j = 0; j < 8; ++j) {
          if ((bmA[j] >> l) & 1) {
            int u = 8 * l + j;
            float cnd = vpA[u] + trans[(size_t)u * Vn + tid];
            if (cnd > bestA) { bestA = cnd; argA = u; }
          }
        }
      }
      float bestB = -3e38f; int argB = 0;
      while (anyB) {
        int l = __ffsll(anyB) - 1; anyB &= anyB - 1;
#pragma unroll
        for (int j = 0; j < 8; ++j) {
          if ((bmB[j] >> l) & 1) {
            int u = 8 * l + j;
            float cnd = vpB[u] + trans[(size_t)u * Vn + tid];
            if (cnd > bestB) { bestB = cnd; argB = u; }
          }
        }
      }
      float nvA = bestA + ecurA; int bpA = argA;
      float nvB = bestB + ecurB; int bpB = argB;
      if (sm.v.padshA[t]) { nvA = vaA; bpA = tid; }
      if (sm.v.padshB[t]) { nvB = vaB; bpB = tid; }
      bps[((size_t)(t - 1) * Bn + bA) * Vn + tid] = (unsigned short)bpA;
      bps[((size_t)(t - 1) * Bn + bB) * Vn + tid] = (unsigned short)bpB;
      sm.v.va2[cur][0][tid] = nvA;
      sm.v.va2[cur][1][tid] = nvB;
      vaA = nvA; ecurA = enA;
      vaB = nvB; ecurB = enB;
      bar_lgkm();  // single barrier per step-pair
    }

    // drain bps stores once, then backtrace per batch
    asm volatile("s_waitcnt vmcnt(0)" ::: "memory");
    __syncthreads();

    for (int bb = 0; bb < 2; ++bb) {
      const int bcur = bb ? bB : bA;
      float fv = bb ? vaB : vaA;
      {
        float val = fv;
        int idx2 = tid;
#pragma unroll
        for (int off = 1; off < 64; off <<= 1) {
          float ov = __shfl_xor(val, off);
          int oi = __shfl_xor(idx2, off);
          if (ov > val || (ov == val && oi < idx2)) { val = ov; idx2 = oi; }
        }
        if (lane == 0) { sm.v.wvals[w] = val; sm.v.widxs[w] = idx2; }
      }
      __syncthreads();
      if (tid == 0) {
        float bv = sm.v.wvals[0]; int bi = sm.v.widxs[0];
        for (int i = 1; i < 8; ++i)
          if (sm.v.wvals[i] > bv || (sm.v.wvals[i] == bv && sm.v.widxs[i] < bi)) {
            bv = sm.v.wvals[i]; bi = sm.v.widxs[i];
          }
        sm.v.lastS = bi;
      }
      __syncthreads();
      int tok = sm.v.lastS;

      for (int cch = 15; cch >= 0; --cch) {
        int rhi = cch * 32 + 31; if (rhi > 510) rhi = 510;
        int srow = tid >> 4, part = tid & 15;
        int row = cch * 32 + srow;
        if (row <= 510) {
          const uint4* src = (const uint4*)(bps + ((size_t)row * Bn + bcur) * Vn);
          uint4* dst = (uint4*)&sm.v.bpbuf[srow][0];
#pragma unroll
          for (int qq = 0; qq < 4; ++qq) dst[part * 4 + qq] = src[part * 4 + qq];
        }
        __syncthreads();
        if (tid == 0) {
          int tk = tok;
          for (int rr = rhi; rr >= cch * 32; --rr) {
            sm.v.tokens[rr + 1] = (unsigned short)tk;
            tk = sm.v.bpbuf[rr - cch * 32][tk];
          }
          tok = tk;
        }
        __syncthreads();
      }
      if (tid == 0) sm.v.tokens[0] = (unsigned short)tok;
      __syncthreads();
      out_tok[bcur * Tn + tid] = (float)sm.v.tokens[tid];
      __syncthreads();
    }
  }
}

extern "C" void kernel_launch(void* const* d_in, const int* in_sizes, int n_in,
                              void* d_out, int out_size, void* d_ws, size_t ws_size,
                              hipStream_t stream) {
  const float* x = (const float*)d_in[0];
  const float* w = (const float*)d_in[1];
  const float* trans = (const float*)d_in[2];
  const int* tgt = (const int*)d_in[3];
  const unsigned char* pad = (const unsigned char*)d_in[4];
  float* out = (float*)d_out;

  char* ws = (char*)d_ws;
  float* Rp = (float*)ws;                                    // 64 B
  unsigned char* E8 = (unsigned char*)(ws + 64);             // 256 KB fp8 fragments
  unsigned short* bps = (unsigned short*)(ws + 64 + 524288); // ~16.7 MB

  float* emis = out;                 // (B,T,V)
  float* out_ll = out + 8388608;     // (B,)
  float* out_tok = out + 8388640;    // (B,T) as float

  hipMemsetAsync(Rp, 0, 4, stream);
  hipLaunchKernelGGL(crf_minmax, dim3(8), dim3(512), 0, stream, trans, (unsigned int*)Rp);
  hipLaunchKernelGGL(crf_build_E8, dim3(128), dim3(256), 0, stream, trans, E8);
  hipLaunchKernelGGL(crf_gemm, dim3(2048), dim3(256), 0, stream, x, w, emis);
  hipLaunchKernelGGL(crf_scan, dim3(32), dim3(512), 0, stream, emis, trans, E8, Rp,
                     tgt, pad, bps, out_ll, out_tok);
}

// Round 12
// 682.109 us; speedup vs baseline: 1.8099x; 1.8099x over previous
//
#include <hip/hip_runtime.h>

#define Bn 32
#define Tn 512
#define Dn 512
#define Vn 512

typedef float f4 __attribute__((ext_vector_type(4)));
typedef int i8v __attribute__((ext_vector_type(8)));
typedef _Float16 h8f __attribute__((ext_vector_type(8)));

__device__ __forceinline__ float max8lds(const float* p) {
  float4 a = *(const float4*)p;
  float4 b = *(const float4*)(p + 4);
  return fmaxf(fmaxf(fmaxf(a.x, a.y), fmaxf(a.z, a.w)),
               fmaxf(fmaxf(b.x, b.y), fmaxf(b.z, b.w)));
}

// 64-lane max via DPP (row_shr 1/2/4/8 + bcast15/31), result broadcast via readlane
__device__ __forceinline__ float dpp64max(float x) {
  int t;
  t = __builtin_amdgcn_update_dpp(__float_as_int(x), __float_as_int(x), 0x111, 0xF, 0xF, false);
  x = fmaxf(x, __int_as_float(t));
  t = __builtin_amdgcn_update_dpp(__float_as_int(x), __float_as_int(x), 0x112, 0xF, 0xF, false);
  x = fmaxf(x, __int_as_float(t));
  t = __builtin_amdgcn_update_dpp(__float_as_int(x), __float_as_int(x), 0x114, 0xF, 0xF, false);
  x = fmaxf(x, __int_as_float(t));
  t = __builtin_amdgcn_update_dpp(__float_as_int(x), __float_as_int(x), 0x118, 0xF, 0xF, false);
  x = fmaxf(x, __int_as_float(t));
  t = __builtin_amdgcn_update_dpp(__float_as_int(x), __float_as_int(x), 0x142, 0xF, 0xF, false);
  x = fmaxf(x, __int_as_float(t));
  t = __builtin_amdgcn_update_dpp(__float_as_int(x), __float_as_int(x), 0x143, 0xF, 0xF, false);
  x = fmaxf(x, __int_as_float(t));
  return __int_as_float(__builtin_amdgcn_readlane(__float_as_int(x), 63));
}

// raw barrier: LDS-visibility only (no vmcnt drain -> global ops float across steps)
__device__ __forceinline__ void bar_lgkm() {
  asm volatile("s_waitcnt lgkmcnt(0)" ::: "memory");
  __builtin_amdgcn_s_barrier();
}

// ---- f32 -> OCP e4m3fn, round-to-nearest-even (x >= 0 assumed) ----
__device__ __forceinline__ unsigned int f32_to_e4m3(float x) {
  x = fminf(x, 448.0f);
  unsigned int bits = __float_as_uint(x);
  int e = (int)((bits >> 23) & 0xFF) - 127;
  if (e < -6) {
    return (unsigned int)__float2int_rn(x * 512.0f);
  }
  unsigned int man = bits & 0x7FFFFF;
  int te = e + 7;
  unsigned int r = man >> 20;
  unsigned int rem = man & 0xFFFFF;
  if (rem > 0x80000u || (rem == 0x80000u && (r & 1u))) r++;
  if (r == 8u) { r = 0u; te++; }
  if (te > 15) { te = 15; r = 6u; }
  unsigned int byte = ((unsigned int)te << 3) | r;
  if (byte > 0x7Eu) byte = 0x7Eu;
  return byte;
}

// ---- pruning radius: max over columns v of (max_u T[u][v] - min_u T[u][v]) ----
__global__ __launch_bounds__(512) void crf_minmax(const float* __restrict__ trans,
                                                  unsigned int* __restrict__ Rout) {
  __shared__ float smn[8][64], smx[8][64];
  const int c = threadIdx.x & 63;
  const int seg = threadIdx.x >> 6;
  const int col = (int)blockIdx.x * 64 + c;
  float mn = 3e38f, mx = -3e38f;
#pragma unroll 4
  for (int u = seg * 64; u < seg * 64 + 64; ++u) {
    float t = trans[(size_t)u * Vn + col];
    mn = fminf(mn, t); mx = fmaxf(mx, t);
  }
  smn[seg][c] = mn; smx[seg][c] = mx;
  __syncthreads();
  if (seg == 0) {
#pragma unroll
    for (int i = 1; i < 8; ++i) { mn = fminf(mn, smn[i][c]); mx = fmaxf(mx, smx[i][c]); }
    float r = dpp64max(mx - mn);  // r >= 0
    if (c == 0) atomicMax((int*)Rout, __float_as_int(r));
  }
}

// ---- E8: exp(trans) as fp8 e4m3 MFMA A-fragments for 16x16x128 ----
// frag (vt, kc): byte index = lane*32 + j
//   u = kc*128 + 32*(lane>>4) + j,  v = vt*16 + (lane&15)
__global__ __launch_bounds__(256) void crf_build_E8(const float* __restrict__ trans,
                                                    unsigned char* __restrict__ E8) {
  const int fid = (int)blockIdx.x;       // 0..127 = vt*4 + kc
  const int vt = fid >> 2, kc = fid & 3;
  const int t = threadIdx.x;             // 8 bytes per thread
  const int lane = t >> 2;
  const int j0 = (t & 3) * 8;
  const int v = vt * 16 + (lane & 15);
  const int ubase = kc * 128 + (lane >> 4) * 32 + j0;
  unsigned long long pack = 0;
#pragma unroll
  for (int s = 0; s < 8; ++s) {
    float e = __expf(trans[(size_t)(ubase + s) * Vn + v]);
    pack |= (unsigned long long)f32_to_e4m3(e) << (8 * s);
  }
  *(unsigned long long*)(E8 + (size_t)fid * 2048 + lane * 32 + j0) = pack;
}

// ---- emissions via split-f16 MFMA (f32-accurate): BM=64, BN=512, BK=32 ----
// x = hi + lo (f16 head + f16 residual); acc += hh + hl + lh + ll (exact products)
// Fragments staged in fragment-contiguous LDS: Wf[nt][lane] (stride-1 b128, no conflicts)
__global__ __launch_bounds__(256) void crf_gemm(const float* __restrict__ X,
                                                const float* __restrict__ Wt,
                                                float* __restrict__ C) {
  __shared__ h8f XfH[4][64], XfL[4][64];    // 8 KB
  __shared__ h8f WfH[32][64], WfL[32][64];  // 64 KB
  const int tid = threadIdx.x;
  const int m0 = (int)blockIdx.x * 64;
  const int wv = tid >> 6, lane = tid & 63;
  const int g = lane >> 4, cc = lane & 15;
  const int srow = tid >> 2;                // 0..63
  const int sc0 = (tid & 3) * 8;            // k-chunk 0/8/16/24
  const int p = (tid & 3) * 16 + ((tid >> 2) & 15);  // fragment slot
  f4 acc[32];
#pragma unroll
  for (int i = 0; i < 32; ++i) acc[i] = (f4)(0.f);

  for (int k0 = 0; k0 < Dn; k0 += 32) {
    __syncthreads();  // protect LDS from previous iteration's reads
    {
      const float* xp = X + (size_t)(m0 + srow) * Dn + k0 + sc0;
      float4 xa = *(const float4*)xp;
      float4 xb = *(const float4*)(xp + 4);
      float xs[8] = {xa.x, xa.y, xa.z, xa.w, xb.x, xb.y, xb.z, xb.w};
      _Float16 hh[8], ll[8];
#pragma unroll
      for (int i = 0; i < 8; ++i) {
        hh[i] = (_Float16)xs[i];
        ll[i] = (_Float16)(xs[i] - (float)hh[i]);
      }
      XfH[tid >> 6][p] = *(h8f*)hh;
      XfL[tid >> 6][p] = *(h8f*)ll;
#pragma unroll
      for (int i = 0; i < 8; ++i) {
        int r = i * 64 + srow;
        const float* wp = Wt + (size_t)r * Dn + k0 + sc0;
        float4 wa = *(const float4*)wp;
        float4 wb = *(const float4*)(wp + 4);
        float wsv[8] = {wa.x, wa.y, wa.z, wa.w, wb.x, wb.y, wb.z, wb.w};
        _Float16 wh[8], wl[8];
#pragma unroll
        for (int q = 0; q < 8; ++q) {
          wh[q] = (_Float16)wsv[q];
          wl[q] = (_Float16)(wsv[q] - (float)wh[q]);
        }
        WfH[i * 4 + (tid >> 6)][p] = *(h8f*)wh;
        WfL[i * 4 + (tid >> 6)][p] = *(h8f*)wl;
      }
    }
    __syncthreads();
    h8f aH = XfH[wv][lane];
    h8f aL = XfL[wv][lane];
#pragma unroll
    for (int nt = 0; nt < 32; ++nt) {
      h8f bH = WfH[nt][lane];
      h8f bL = WfL[nt][lane];
      acc[nt] = __builtin_amdgcn_mfma_f32_16x16x32_f16(aH, bH, acc[nt], 0, 0, 0);
      acc[nt] = __builtin_amdgcn_mfma_f32_16x16x32_f16(aH, bL, acc[nt], 0, 0, 0);
      acc[nt] = __builtin_amdgcn_mfma_f32_16x16x32_f16(aL, bH, acc[nt], 0, 0, 0);
      acc[nt] = __builtin_amdgcn_mfma_f32_16x16x32_f16(aL, bL, acc[nt], 0, 0, 0);
    }
  }
#pragma unroll
  for (int nt = 0; nt < 32; ++nt)
#pragma unroll
    for (int r = 0; r < 4; ++r)
      C[(size_t)(m0 + wv * 16 + 4 * g + r) * Vn + nt * 16 + cc] = acc[nt][r];
}

// ---- shared-memory union: forward vs viterbi roles ----
union SM {
  struct {
    __align__(16) unsigned char ph[Vn];   // fp8 p broadcast (512 B)
    __align__(16) float wred[8];
    __align__(16) float wred2[8];
    unsigned char padsh[Tn];
  } f;
  struct {
    __align__(16) float va2[2][Vn];
    __align__(16) unsigned short bpbuf[32][Vn];
    unsigned short tokens[Tn];
    __align__(16) float wvals[8];
    int widxs[8];
    unsigned char padsh[Tn];
    int lastS;
  } v;
};

// ---- fused scan: blocks 0..31 forward(logZ,loglik); 32..63 viterbi+backtrace ----
__global__ __launch_bounds__(512, 2) void crf_scan(
    const float* __restrict__ emis, const float* __restrict__ trans,
    const unsigned char* __restrict__ E8, const float* __restrict__ Rp,
    const int* __restrict__ tgt, const unsigned char* __restrict__ pad,
    unsigned short* __restrict__ bps, float* __restrict__ out_ll,
    float* __restrict__ out_tok) {
  __shared__ SM sm;

  const int tid = threadIdx.x;
  const int b = blockIdx.x & 31;
  const int role = blockIdx.x >> 5;
  const float* eb = emis + (size_t)b * Tn * Vn;
  const int w = tid >> 6;
  const int lane = tid & 63;

  if (role == 0) {
    // ========== FORWARD (logsumexp via MX-FP8 MFMA K=128, exact-m 2-barrier) ==========
    const int g = lane >> 4, c = lane & 15;
    const int t2sel = c >> 2, r2sel = c & 3;
    const int sidx = ((16 * ((lane >> 2) & 3)) + 4 * (lane >> 4) + (lane & 3)) << 2;
    // all of E resident: 4 v-tiles x 4 kc x 8 dwords = 128 VGPRs
    i8v EA[4][4];
    {
      const i8v* E8v = (const i8v*)E8;
#pragma unroll
      for (int vt2 = 0; vt2 < 4; ++vt2)
#pragma unroll
        for (int kc = 0; kc < 4; ++kc)
          EA[vt2][kc] = E8v[((4 * w + vt2) * 4 + kc) * 64 + lane];
    }
    sm.f.padsh[tid] = pad[b * Tn + tid];
    float alphaR = eb[tid];
    float ecur = eb[Vn + tid];
    {
      float r = dpp64max(alphaR);
      if (lane == 0) sm.f.wred[w] = r;
    }
    bar_lgkm();
    float m = max8lds(sm.f.wred);  // exact max(alpha_{t-1}) at loop top

    for (int t = 1; t < Tn; ++t) {
      float p = __expf(alphaR - m);            // p in (0, 1]
      sm.f.ph[tid] = (unsigned char)f32_to_e4m3(p);
      bar_lgkm();  // A: ph visible
      float enext = (t + 1 < Tn) ? eb[(size_t)(t + 1) * Vn + tid] : 0.f;
      // B fragments: 32 bytes per lane-group g per kc (broadcast reads)
      const uint4* phq = (const uint4*)sm.f.ph;
      i8v B4[4];
#pragma unroll
      for (int kc = 0; kc < 4; ++kc) {
        union { uint4 u[2]; i8v v; } bu;
        bu.u[0] = phq[kc * 8 + g * 2];
        bu.u[1] = phq[kc * 8 + g * 2 + 1];
        B4[kc] = bu.v;
      }
      f4 acc0 = (f4)(0.f), acc1 = (f4)(0.f), acc2 = (f4)(0.f), acc3 = (f4)(0.f);
#pragma unroll
      for (int kc = 0; kc < 4; ++kc) {
        acc0 = __builtin_amdgcn_mfma_scale_f32_16x16x128_f8f6f4(
            EA[0][kc], B4[kc], acc0, 0, 0, 0, 0x7F7F7F7F, 0, 0x7F7F7F7F);
        acc1 = __builtin_amdgcn_mfma_scale_f32_16x16x128_f8f6f4(
            EA[1][kc], B4[kc], acc1, 0, 0, 0, 0x7F7F7F7F, 0, 0x7F7F7F7F);
        acc2 = __builtin_amdgcn_mfma_scale_f32_16x16x128_f8f6f4(
            EA[2][kc], B4[kc], acc2, 0, 0, 0, 0x7F7F7F7F, 0, 0x7F7F7F7F);
        acc3 = __builtin_amdgcn_mfma_scale_f32_16x16x128_f8f6f4(
            EA[3][kc], B4[kc], acc3, 0, 0, 0, 0x7F7F7F7F, 0, 0x7F7F7F7F);
      }
      // lane (g,c) holds D[4g+r][c] of tile t2sel; one intra-wave bpermute redistributes
      f4 at = (t2sel == 0) ? acc0 : (t2sel == 1) ? acc1 : (t2sel == 2) ? acc2 : acc3;
      float lo = (r2sel & 1) ? at[1] : at[0];
      float hi = (r2sel & 1) ? at[3] : at[2];
      float tot = (r2sel & 2) ? hi : lo;
      float tv = __int_as_float(__builtin_amdgcn_ds_bpermute(sidx, __float_as_int(tot)));
      float nv = m + __logf(tv) + ecur;
      if (sm.f.padsh[t]) nv = alphaR;
      alphaR = nv; ecur = enext;
      float rmx = dpp64max(nv);
      if (lane == 0) sm.f.wred[w] = rmx;
      bar_lgkm();  // B: wred visible; ph safe to overwrite next iter
      m = max8lds(sm.f.wred);  // exact max(alpha_t)
    }

    // epilogue: logZ + gold score (m = exact max alpha_511)
    __syncthreads();
    float ex = __expf(alphaR - m);
#pragma unroll
    for (int off = 1; off < 64; off <<= 1) ex += __shfl_xor(ex, off);
    if (lane == 0) sm.f.wred[w] = ex;
    float sc;
    {
      int t = tid;
      int tg = tgt[b * Tn + t];
      float mt = sm.f.padsh[t] ? 0.f : 1.f;
      sc = eb[(size_t)t * Vn + tg] * mt;
      if (t < Tn - 1) {
        int tg1 = tgt[b * Tn + t + 1];
        float mt1 = sm.f.padsh[t + 1] ? 0.f : 1.f;
        sc += trans[(size_t)tg * Vn + tg1] * mt * mt1;
      }
    }
#pragma unroll
    for (int off = 1; off < 64; off <<= 1) sc += __shfl_xor(sc, off);
    if (lane == 0) sm.f.wred2[w] = sc;
    __syncthreads();
    if (tid == 0) {
      float s = 0.f, gg = 0.f;
      for (int i = 0; i < 8; ++i) { s += sm.f.wred[i]; gg += sm.f.wred2[i]; }
      out_ll[b] = gg - (m + __logf(s));
    }
  } else {
    // ========== VITERBI (1 barrier/step, GLOBAL threshold, wave-redundant masks) ==========
    float R = __int_as_float(((const int*)Rp)[0]) * 1.000001f + 1e-4f;
    sm.v.padsh[tid] = pad[b * Tn + tid];
    float vaR = eb[tid];
    sm.v.va2[0][tid] = vaR;
    float ecur = eb[Vn + tid];
    bar_lgkm();

    for (int t = 1; t < Tn; ++t) {
      const int cur = t & 1, prev = cur ^ 1;
      const float* va2p = sm.v.va2[prev];
      const float4* vap4 = (const float4*)va2p;
      float4 q0 = vap4[lane * 2];
      float4 q1 = vap4[lane * 2 + 1];
      float mx8 = fmaxf(fmaxf(fmaxf(q0.x, q0.y), fmaxf(q0.z, q0.w)),
                        fmaxf(fmaxf(q1.x, q1.y), fmaxf(q1.z, q1.w)));
      float gmax = dpp64max(mx8);
      float thr = gmax - R;
      unsigned long long bm[8];
      bm[0] = __ballot(q0.x >= thr);
      bm[1] = __ballot(q0.y >= thr);
      bm[2] = __ballot(q0.z >= thr);
      bm[3] = __ballot(q0.w >= thr);
      bm[4] = __ballot(q1.x >= thr);
      bm[5] = __ballot(q1.y >= thr);
      bm[6] = __ballot(q1.z >= thr);
      bm[7] = __ballot(q1.w >= thr);
      unsigned long long any = bm[0] | bm[1] | bm[2] | bm[3] |
                               bm[4] | bm[5] | bm[6] | bm[7];
      float enext = (t + 1 < Tn) ? eb[(size_t)(t + 1) * Vn + tid] : 0.f;
      float best = -3e38f; int arg = 0;
      while (any) {  // ascending l (wave-uniform), j ascending -> ascending u
        int l = __ffsll(any) - 1; any &= any - 1;
#pragma unroll
        for (int j = 0; j < 8; ++j) {
          if ((bm[j] >> l) & 1) {
            int u = 8 * l + j;
            float cnd = va2p[u] + trans[(size_t)u * Vn + tid];
            if (cnd > best) { best = cnd; arg = u; }
          }
        }
      }
      float nv = best + ecur; int bp = arg;
      if (sm.v.padsh[t]) { nv = vaR; bp = tid; }
      bps[((size_t)(t - 1) * Bn + b) * Vn + tid] = (unsigned short)bp;  // floats free
      sm.v.va2[cur][tid] = nv;
      vaR = nv; ecur = enext;
      bar_lgkm();  // single barrier: va2[cur] visible
    }

    // drain bps stores once, then backtrace
    asm volatile("s_waitcnt vmcnt(0)" ::: "memory");
    __syncthreads();

    {
      float val = vaR;
      int idx = tid;
#pragma unroll
      for (int off = 1; off < 64; off <<= 1) {
        float ov = __shfl_xor(val, off);
        int oi = __shfl_xor(idx, off);
        if (ov > val || (ov == val && oi < idx)) { val = ov; idx = oi; }
      }
      if (lane == 0) { sm.v.wvals[w] = val; sm.v.widxs[w] = idx; }
    }
    __syncthreads();
    if (tid == 0) {
      float bv = sm.v.wvals[0]; int bi = sm.v.widxs[0];
      for (int i = 1; i < 8; ++i)
        if (sm.v.wvals[i] > bv || (sm.v.wvals[i] == bv && sm.v.widxs[i] < bi)) {
          bv = sm.v.wvals[i]; bi = sm.v.widxs[i];
        }
      sm.v.lastS = bi;
    }
    __syncthreads();
    int tok = sm.v.lastS;

    // backtrace: rows 510..0, 32-row LDS chunks
    for (int cch = 15; cch >= 0; --cch) {
      int rhi = cch * 32 + 31; if (rhi > 510) rhi = 510;
      int srow = tid >> 4, part = tid & 15;
      int row = cch * 32 + srow;
      if (row <= 510) {
        const uint4* src = (const uint4*)(bps + ((size_t)row * Bn + b) * Vn);
        uint4* dst = (uint4*)&sm.v.bpbuf[srow][0];
#pragma unroll
        for (int qq = 0; qq < 4; ++qq) dst[part * 4 + qq] = src[part * 4 + qq];
      }
      __syncthreads();
      if (tid == 0) {
        int tk = tok;
        for (int rr = rhi; rr >= cch * 32; --rr) {
          sm.v.tokens[rr + 1] = (unsigned short)tk;
          tk = sm.v.bpbuf[rr - cch * 32][tk];
        }
        tok = tk;
      }
      __syncthreads();
    }
    if (tid == 0) sm.v.tokens[0] = (unsigned short)tok;
    __syncthreads();
    out_tok[b * Tn + tid] = (float)sm.v.tokens[tid];
  }
}

extern "C" void kernel_launch(void* const* d_in, const int* in_sizes, int n_in,
                              void* d_out, int out_size, void* d_ws, size_t ws_size,
                              hipStream_t stream) {
  const float* x = (const float*)d_in[0];
  const float* w = (const float*)d_in[1];
  const float* trans = (const float*)d_in[2];
  const int* tgt = (const int*)d_in[3];
  const unsigned char* pad = (const unsigned char*)d_in[4];
  float* out = (float*)d_out;

  char* ws = (char*)d_ws;
  float* Rp = (float*)ws;                                    // 64 B
  unsigned char* E8 = (unsigned char*)(ws + 64);             // 256 KB fp8 fragments
  unsigned short* bps = (unsigned short*)(ws + 64 + 524288); // ~16.7 MB

  float* emis = out;                 // (B,T,V)
  float* out_ll = out + 8388608;     // (B,)
  float* out_tok = out + 8388640;    // (B,T) as float

  (void)hipMemsetAsync(Rp, 0, 4, stream);
  hipLaunchKernelGGL(crf_minmax, dim3(8), dim3(512), 0, stream, trans, (unsigned int*)Rp);
  hipLaunchKernelGGL(crf_build_E8, dim3(128), dim3(256), 0, stream, trans, E8);
  hipLaunchKernelGGL(crf_gemm, dim3(256), dim3(256), 0, stream, x, w, emis);
  hipLaunchKernelGGL(crf_scan, dim3(64), dim3(512), 0, stream, emis, trans, E8, Rp,
                     tgt, pad, bps, out_ll, out_tok);
}